// Round 7
// baseline (768.562 us; speedup 1.0000x reference)
//
#include <hip/hip_runtime.h>

// GCN: 3 x (GCNConv -> BN(train) -> PReLU), N=100000, E=1600000, 128->64->64->64
// R7: temporal L2 blocking in aggregate: each wave owns 12 contiguous nodes
//     with persistent float4 register accumulators, OUTER loop over 4
//     src-ranges (3.2MB hsb slice < 4MB per-XCD L2). Whole device sweeps
//     ranges in order -> concurrently-hot gather slice ~3.2MB.
// R6 lesson: per-row range grouping alone = no temporal blocking (FETCH
//     unchanged 162MB). R5 lesson: gather MLP depth >1 thrashes L2.
// R3 lesson: per-bucket LDS-atomic aggregation = latency disaster.

constexpr float BN_EPS = 1e-5f;
constexpr int NB_SHIFT = 7;          // 128 nodes per bucket
constexpr int BCAP = 2560;           // pairs per bucket (avg 2048, ~11 sigma)
constexpr int PART_CHUNK = 8192;     // edges per partition block
constexpr int KNODES = 12;           // nodes owned per wave
constexpr int AGG_BLOCKS = 2112;     // 2112*4 waves * 12 nodes = 101376 >= N

__device__ inline float bf2f(unsigned short h) {
    return __uint_as_float(((unsigned)h) << 16);
}
__device__ inline unsigned short f2bf(float f) {
    unsigned u = __float_as_uint(f);
    unsigned r = (u + 0x7FFFu + ((u >> 16) & 1u)) >> 16;
    return (unsigned short)r;
}

// Partition edges into 128-node dst-buckets (run-contiguous pair writes).
__global__ __launch_bounds__(256) void partition_edges(
    const int* __restrict__ src, const int* __restrict__ dst,
    int* __restrict__ bcount, uint2* __restrict__ pairs, int E, int nbuck) {
    __shared__ int hist[1024];
    const int t = threadIdx.x;
    for (int i = t; i < nbuck; i += 256) hist[i] = 0;
    __syncthreads();
    const int e0 = blockIdx.x * PART_CHUNK;
    const int e1 = min(e0 + PART_CHUNK, E);
    for (int e = e0 + t; e < e1; e += 256)
        atomicAdd(&hist[dst[e] >> NB_SHIFT], 1);
    __syncthreads();
    for (int i = t; i < nbuck; i += 256) {
        int c = hist[i];
        hist[i] = (c > 0) ? atomicAdd(&bcount[i], c) : 0;  // run base within bucket
    }
    __syncthreads();
    for (int e = e0 + t; e < e1; e += 256) {
        int s = src[e], d = dst[e];
        int b = d >> NB_SHIFT;
        int pos = atomicAdd(&hist[b], 1);
        pairs[(size_t)b * BCAP + pos] = make_uint2((unsigned)s, (unsigned)d);
    }
}

// Exclusive scan of bcount[nbuck] -> bbase; also rowstart[N] = E sentinel.
__global__ __launch_bounds__(1024) void scan_bcount(
    const int* __restrict__ bcount, int* __restrict__ bbase,
    int* __restrict__ rowstart, int N, int E, int nbuck) {
    __shared__ int tmp[1024];
    const int t = threadIdx.x;
    int v = (t < nbuck) ? bcount[t] : 0;
    tmp[t] = v;
    __syncthreads();
    for (int off = 1; off < 1024; off <<= 1) {
        int u = (t >= off) ? tmp[t - off] : 0;
        __syncthreads();
        tmp[t] += u;
        __syncthreads();
    }
    if (t < nbuck) bbase[t] = tmp[t] - v;  // exclusive
    if (t == 0) rowstart[N] = E;
}

// One block per bucket: per-(node, src-range) LDS histogram -> scan ->
// rowstart/dinv/rowr4, then cursor fill of col, entries of each row grouped
// by src-range. rowr4[n] = global col offsets of the 4 range segments.
__global__ __launch_bounds__(256) void fill_csr_bucket(
    const uint2* __restrict__ pairs, const int* __restrict__ bcount,
    const int* __restrict__ bbase, int* __restrict__ rowstart,
    int4* __restrict__ rowr4, float* __restrict__ dinv,
    int* __restrict__ col, int N, float rinv) {
    __shared__ int hist[512];    // (node, range) counts -> cursors
    __shared__ int ndeg[128], pfx[128];
    const int b = blockIdx.x, t = threadIdx.x;
    for (int i = t; i < 512; i += 256) hist[i] = 0;
    __syncthreads();
    const int cnt = bcount[b];
    const uint2* pp = pairs + (size_t)b * BCAP;
    for (int e = t; e < cnt; e += 256) {
        uint2 pr = pp[e];
        int rg = min(3, (int)((float)pr.x * rinv));
        atomicAdd(&hist[(int)(pr.y & 127u) * 4 + rg], 1);
    }
    __syncthreads();
    if (t < 128) {
        int d = hist[t * 4] + hist[t * 4 + 1] + hist[t * 4 + 2] + hist[t * 4 + 3];
        ndeg[t] = d;
        pfx[t] = d;
    }
    __syncthreads();
    for (int off = 1; off < 128; off <<= 1) {
        int v = 0;
        if (t < 128 && t >= off) v = pfx[t - off];
        __syncthreads();
        if (t < 128) pfx[t] += v;
        __syncthreads();
    }
    const int base = bbase[b];
    if (t < 128) {
        int deg = ndeg[t];
        int start = base + pfx[t] - deg;  // exclusive within bucket
        int n = (b << NB_SHIFT) + t;
        int c0 = start;
        int c1 = c0 + hist[t * 4 + 0];
        int c2 = c1 + hist[t * 4 + 1];
        int c3 = c2 + hist[t * 4 + 2];
        if (n < N) {
            rowstart[n] = start;
            rowr4[n] = make_int4(c0, c1, c2, c3);
            dinv[n] = rsqrtf((float)deg + 1.0f);  // +1 self-loop
        }
        hist[t * 4 + 0] = c0; hist[t * 4 + 1] = c1;
        hist[t * 4 + 2] = c2; hist[t * 4 + 3] = c3;
    }
    __syncthreads();
    for (int e = t; e < cnt; e += 256) {
        uint2 pr = pp[e];
        int rg = min(3, (int)((float)pr.x * rinv));
        int pos = atomicAdd(&hist[(int)(pr.y & 127u) * 4 + rg], 1);
        col[pos] = (int)pr.x;
    }
}

// hs[row][c] = (X'[row][:] @ W[:][c]) * dinv[row], stored bf16.
// FUSE: X' = prelu(X*scale + shift, a) applied per-column during staging.
template <int K, bool FUSE>
__global__ __launch_bounds__(256) void gemm_scale(
    const float* __restrict__ X, const float* __restrict__ W,
    const float* __restrict__ dinv, const float* __restrict__ stats_prev,
    const float* __restrict__ a_prev, ushort4* __restrict__ hsb4, int N) {
    static_assert(K % 64 == 0, "K must be multiple of 64");
    __shared__ float Ws[K * 64];
    __shared__ float Xs[64 * 65];

    const int t = threadIdx.x;
    const int rowBase = blockIdx.x * 64;

    for (int q = t; q < K * 16; q += 256)
        ((float4*)Ws)[q] = ((const float4*)W)[q];

    const int tx = t & 15;
    const int ty = t >> 4;

    float acc[4][4];
#pragma unroll
    for (int i = 0; i < 4; ++i)
#pragma unroll
        for (int j = 0; j < 4; ++j) acc[i][j] = 0.f;

#pragma unroll
    for (int kh = 0; kh < K / 64; ++kh) {
        __syncthreads();
#pragma unroll
        for (int j = 0; j < 4; ++j) {
            int q = t + j * 256;
            int r = q >> 4, kk = q & 15;
            int row = rowBase + r;
            float4 v = make_float4(0.f, 0.f, 0.f, 0.f);
            if (row < N) {
                v = *(const float4*)(X + (size_t)row * K + kh * 64 + kk * 4);
                if (FUSE) {
                    int cg = kh * 16 + kk;
                    float4 sc = ((const float4*)(stats_prev + 128))[cg];
                    float4 sh = ((const float4*)(stats_prev + 192))[cg];
                    float4 av = ((const float4*)a_prev)[cg];
                    v.x = fmaf(v.x, sc.x, sh.x); v.x = v.x >= 0.f ? v.x : av.x * v.x;
                    v.y = fmaf(v.y, sc.y, sh.y); v.y = v.y >= 0.f ? v.y : av.y * v.y;
                    v.z = fmaf(v.z, sc.z, sh.z); v.z = v.z >= 0.f ? v.z : av.z * v.z;
                    v.w = fmaf(v.w, sc.w, sh.w); v.w = v.w >= 0.f ? v.w : av.w * v.w;
                }
            }
            float* p = &Xs[r * 65 + kk * 4];
            p[0] = v.x; p[1] = v.y; p[2] = v.z; p[3] = v.w;
        }
        __syncthreads();
#pragma unroll 8
        for (int k = 0; k < 64; ++k) {
            float4 w4 = *(const float4*)&Ws[(kh * 64 + k) * 64 + tx * 4];
#pragma unroll
            for (int i = 0; i < 4; ++i) {
                float xv = Xs[(ty * 4 + i) * 65 + k];
                acc[i][0] = fmaf(xv, w4.x, acc[i][0]);
                acc[i][1] = fmaf(xv, w4.y, acc[i][1]);
                acc[i][2] = fmaf(xv, w4.z, acc[i][2]);
                acc[i][3] = fmaf(xv, w4.w, acc[i][3]);
            }
        }
    }

#pragma unroll
    for (int i = 0; i < 4; ++i) {
        int row = rowBase + ty * 4 + i;
        if (row < N) {
            float dv = dinv[row];
            ushort4 o;
            o.x = f2bf(acc[i][0] * dv);
            o.y = f2bf(acc[i][1] * dv);
            o.z = f2bf(acc[i][2] * dv);
            o.w = f2bf(acc[i][3] * dv);
            hsb4[(size_t)row * 16 + tx] = o;
        }
    }
}

// Each wave owns KNODES contiguous nodes; persistent float4 register accs;
// outer loop over 4 src-ranges so the device-wide hot gather slice is 3.2MB.
__global__ __launch_bounds__(256) void aggregate_bn(
    const ushort4* __restrict__ hsb4, const int* __restrict__ col,
    const int* __restrict__ rowstart, const int4* __restrict__ rowr4,
    const float* __restrict__ dinv, const float* __restrict__ bias,
    float* __restrict__ stats, float4* __restrict__ y4, int N) {
    const int t = threadIdx.x;
    const int lane = t & 63;
    const int wid = t >> 6;      // wave in block (0..3)
    const int fl = lane & 15;    // float4 feature index
    const int eg = lane >> 4;    // edge subgroup (0..3)

    __shared__ float lsum[64], lsq[64];
    if (t < 64) { lsum[t] = 0.f; lsq[t] = 0.f; }
    __syncthreads();

    const int nbase = (blockIdx.x * 4 + wid) * KNODES;

    float4 acc[KNODES];
#pragma unroll
    for (int k = 0; k < KNODES; ++k)
        acc[k] = make_float4(0.f, 0.f, 0.f, 0.f);

    for (int r = 0; r < 4; ++r) {
#pragma unroll
        for (int k = 0; k < KNODES; ++k) {
            int n = nbase + k;
            if (n < N) {
                int4 c4 = rowr4[n];
                int cs = (r == 0) ? c4.x : (r == 1) ? c4.y : (r == 2) ? c4.z : c4.w;
                int ce = (r == 0) ? c4.y : (r == 1) ? c4.z : (r == 2) ? c4.w
                                                          : rowstart[n + 1];
                for (int i = cs + eg; i < ce; i += 4) {
                    int s = col[i];
                    ushort4 rv = hsb4[(size_t)s * 16 + fl];
                    acc[k].x += bf2f(rv.x); acc[k].y += bf2f(rv.y);
                    acc[k].z += bf2f(rv.z); acc[k].w += bf2f(rv.w);
                }
            }
        }
    }

    float4 ssum = make_float4(0.f, 0.f, 0.f, 0.f);
    float4 ssq  = make_float4(0.f, 0.f, 0.f, 0.f);
    const float4 b4 = ((const float4*)bias)[fl];

#pragma unroll
    for (int k = 0; k < KNODES; ++k) {
        int n = nbase + k;
        if (n >= N) break;
        float4 a = acc[k];
        a.x += __shfl_xor(a.x, 16); a.y += __shfl_xor(a.y, 16);
        a.z += __shfl_xor(a.z, 16); a.w += __shfl_xor(a.w, 16);
        a.x += __shfl_xor(a.x, 32); a.y += __shfl_xor(a.y, 32);
        a.z += __shfl_xor(a.z, 32); a.w += __shfl_xor(a.w, 32);
        if (eg == 0) {
            ushort4 sv = hsb4[(size_t)n * 16 + fl];
            float dv = dinv[n];
            float4 yv;
            yv.x = fmaf(dv, a.x + bf2f(sv.x), b4.x);
            yv.y = fmaf(dv, a.y + bf2f(sv.y), b4.y);
            yv.z = fmaf(dv, a.z + bf2f(sv.z), b4.z);
            yv.w = fmaf(dv, a.w + bf2f(sv.w), b4.w);
            y4[(size_t)n * 16 + fl] = yv;
            ssum.x += yv.x; ssum.y += yv.y; ssum.z += yv.z; ssum.w += yv.w;
            ssq.x = fmaf(yv.x, yv.x, ssq.x); ssq.y = fmaf(yv.y, yv.y, ssq.y);
            ssq.z = fmaf(yv.z, yv.z, ssq.z); ssq.w = fmaf(yv.w, yv.w, ssq.w);
        }
    }
    if (eg == 0) {
        atomicAdd(&lsum[fl * 4 + 0], ssum.x); atomicAdd(&lsum[fl * 4 + 1], ssum.y);
        atomicAdd(&lsum[fl * 4 + 2], ssum.z); atomicAdd(&lsum[fl * 4 + 3], ssum.w);
        atomicAdd(&lsq[fl * 4 + 0], ssq.x);  atomicAdd(&lsq[fl * 4 + 1], ssq.y);
        atomicAdd(&lsq[fl * 4 + 2], ssq.z);  atomicAdd(&lsq[fl * 4 + 3], ssq.w);
    }
    __syncthreads();
    if (t < 64) atomicAdd(&stats[t], lsum[t]);
    else if (t < 128) atomicAdd(&stats[64 + (t - 64)], lsq[t - 64]);
}

__global__ void bn_final(float* __restrict__ stats, const float* __restrict__ g,
                         const float* __restrict__ be, float invN) {
    int c = threadIdx.x;  // 64 threads
    float mu = stats[c] * invN;
    float var = stats[64 + c] * invN - mu * mu;
    float sc = g[c] * rsqrtf(var + BN_EPS);
    stats[128 + c] = sc;
    stats[192 + c] = be[c] - mu * sc;
}

// final layer only: out = prelu(y*scale + shift, a)
__global__ __launch_bounds__(256) void bn_apply(
    const float4* __restrict__ y4, const float* __restrict__ stats,
    const float* __restrict__ a, float4* __restrict__ out4, int total4) {
    int i = blockIdx.x * blockDim.x + threadIdx.x;
    if (i >= total4) return;
    int cg = (i & 15) * 4;
    float4 v = y4[i];
    float4 o;
    { float z = fmaf(v.x, stats[128 + cg + 0], stats[192 + cg + 0]); o.x = z >= 0.f ? z : a[cg + 0] * z; }
    { float z = fmaf(v.y, stats[128 + cg + 1], stats[192 + cg + 1]); o.y = z >= 0.f ? z : a[cg + 1] * z; }
    { float z = fmaf(v.z, stats[128 + cg + 2], stats[192 + cg + 2]); o.z = z >= 0.f ? z : a[cg + 2] * z; }
    { float z = fmaf(v.w, stats[128 + cg + 3], stats[192 + cg + 3]); o.w = z >= 0.f ? z : a[cg + 3] * z; }
    out4[i] = o;
}

extern "C" void kernel_launch(void* const* d_in, const int* in_sizes, int n_in,
                              void* d_out, int out_size, void* d_ws, size_t ws_size,
                              hipStream_t stream) {
    const float* x  = (const float*)d_in[0];
    const int*   ei = (const int*)d_in[1];
    const int N = in_sizes[0] / 128;
    const int E = in_sizes[1] / 2;
    const int* srcp = ei;
    const int* dstp = ei + E;

    const float* W1 = (const float*)d_in[2];
    const float* b1 = (const float*)d_in[3];
    const float* g1 = (const float*)d_in[4];
    const float* be1 = (const float*)d_in[5];
    const float* a1 = (const float*)d_in[6];
    const float* W2 = (const float*)d_in[7];
    const float* b2 = (const float*)d_in[8];
    const float* g2 = (const float*)d_in[9];
    const float* be2 = (const float*)d_in[10];
    const float* a2 = (const float*)d_in[11];
    const float* W3 = (const float*)d_in[12];
    const float* b3 = (const float*)d_in[13];
    const float* g3 = (const float*)d_in[14];
    const float* be3 = (const float*)d_in[15];
    const float* a3 = (const float*)d_in[16];

    const int nbuck = (N + 127) >> NB_SHIFT;  // 782
    const int rdiv = (N + 3) / 4;             // src-range width (~25000)
    const float rinv = 1.0f / (float)rdiv;

    // ws layout (4B units):
    // dinv[N] | rowstart[N+4] | rowr4[4N] | bcount[1024] | bbase[1024] |
    // stats[768] | col[E] | pairs[nbuck*BCAP*2] | hsb[N*32] | ybuf[N*64]
    float* ws = (float*)d_ws;
    float* dinv     = ws;
    int*   rowstart = (int*)(ws + N);
    int4*  rowr4    = (int4*)(ws + 2 * (size_t)N + 4);
    int*   bcount   = (int*)(ws + 6 * (size_t)N + 4);
    int*   bbase    = bcount + 1024;
    float* stats    = (float*)(bbase + 1024);
    int*   col      = (int*)(stats + 768);
    uint2* pairs    = (uint2*)(col + E);
    float* hsbf     = (float*)(pairs + (size_t)nbuck * BCAP);
    ushort4* hsb4   = (ushort4*)hsbf;
    float* ybuf     = hsbf + (size_t)N * 32;

    float* stats1 = stats, *stats2 = stats + 256, *stats3 = stats + 512;

    // one memset covers bcount + bbase + stats (contiguous)
    hipMemsetAsync(bcount, 0, (1024 + 1024 + 768) * sizeof(int), stream);
    partition_edges<<<(E + PART_CHUNK - 1) / PART_CHUNK, 256, 0, stream>>>(
        srcp, dstp, bcount, pairs, E, nbuck);
    scan_bcount<<<1, 1024, 0, stream>>>(bcount, bbase, rowstart, N, E, nbuck);
    fill_csr_bucket<<<nbuck, 256, 0, stream>>>(pairs, bcount, bbase, rowstart,
                                               rowr4, dinv, col, N, rinv);

    const int gemmGrid = (N + 63) / 64;
    const int applyGrid = (N * 16 + 255) / 256;
    const float invN = 1.0f / (float)N;

    // ---- layer 1 ----
    gemm_scale<128, false><<<gemmGrid, 256, 0, stream>>>(x, W1, dinv, nullptr, nullptr, hsb4, N);
    aggregate_bn<<<AGG_BLOCKS, 256, 0, stream>>>(hsb4, col, rowstart, rowr4, dinv,
                                                 b1, stats1, (float4*)ybuf, N);
    bn_final<<<1, 64, 0, stream>>>(stats1, g1, be1, invN);

    // ---- layer 2 (BN1+PReLU1 fused into X staging) ----
    gemm_scale<64, true><<<gemmGrid, 256, 0, stream>>>(ybuf, W2, dinv, stats1, a1, hsb4, N);
    aggregate_bn<<<AGG_BLOCKS, 256, 0, stream>>>(hsb4, col, rowstart, rowr4, dinv,
                                                 b2, stats2, (float4*)ybuf, N);
    bn_final<<<1, 64, 0, stream>>>(stats2, g2, be2, invN);

    // ---- layer 3 ----
    gemm_scale<64, true><<<gemmGrid, 256, 0, stream>>>(ybuf, W3, dinv, stats2, a2, hsb4, N);
    aggregate_bn<<<AGG_BLOCKS, 256, 0, stream>>>(hsb4, col, rowstart, rowr4, dinv,
                                                 b3, stats3, (float4*)ybuf, N);
    bn_final<<<1, 64, 0, stream>>>(stats3, g3, be3, invN);

    bn_apply<<<applyGrid, 256, 0, stream>>>((const float4*)ybuf, stats3, a3,
                                            (float4*)d_out, N * 16);
}

// Round 8
// 607.961 us; speedup vs baseline: 1.2642x; 1.2642x over previous
//
#include <hip/hip_runtime.h>

// GCN: 3 x (GCNConv -> BN(train) -> PReLU), N=100000, E=1600000, 128->64->64->64
// R8: aggregate gather widened to 8 lanes x 16B per edge (8 edges in flight
//     per wave instruction vs 4) with flat depth-1 loop; packed uint pairs;
//     bn_final eliminated (scale/shift inlined into consumers). 11 dispatches.
// Evidence: FETCH ~90-100MB is per-XCD compulsory floor (8 XCD x 12.8MB table)
//     - locality engineering is dead (R6 no-op, R7 regression). Throughput of
//     the L2-miss path scales with in-flight edges (R4 1.16 TB/s @4/wave,
//     R5 1.68 TB/s @16/wave but depth-unroll bloated FETCH to 162MB).
// R3 lesson: per-bucket LDS-atomic aggregation = latency disaster.

constexpr float BN_EPS = 1e-5f;
constexpr int NB_SHIFT = 7;          // 128 nodes per bucket
constexpr int BCAP = 2560;           // pairs per bucket (avg 2048, ~11 sigma)
constexpr int PART_CHUNK = 8192;     // edges per partition block

__device__ inline float bf_lo(unsigned u) { return __uint_as_float(u << 16); }
__device__ inline float bf_hi(unsigned u) { return __uint_as_float(u & 0xffff0000u); }
__device__ inline unsigned short f2bf(float f) {
    unsigned u = __float_as_uint(f);
    unsigned r = (u + 0x7FFFu + ((u >> 16) & 1u)) >> 16;
    return (unsigned short)r;
}

// Partition edges into 128-node dst-buckets; packed entry = src | (local<<20)
// (N < 2^20; local dst-in-bucket is 7 bits).
__global__ __launch_bounds__(256) void partition_edges(
    const int* __restrict__ src, const int* __restrict__ dst,
    int* __restrict__ bcount, unsigned* __restrict__ pairs, int E, int nbuck) {
    __shared__ int hist[1024];
    const int t = threadIdx.x;
    for (int i = t; i < nbuck; i += 256) hist[i] = 0;
    __syncthreads();
    const int e0 = blockIdx.x * PART_CHUNK;
    const int e1 = min(e0 + PART_CHUNK, E);
    for (int e = e0 + t; e < e1; e += 256)
        atomicAdd(&hist[dst[e] >> NB_SHIFT], 1);
    __syncthreads();
    for (int i = t; i < nbuck; i += 256) {
        int c = hist[i];
        hist[i] = (c > 0) ? atomicAdd(&bcount[i], c) : 0;  // run base within bucket
    }
    __syncthreads();
    for (int e = e0 + t; e < e1; e += 256) {
        int s = src[e], d = dst[e];
        int b = d >> NB_SHIFT;
        int pos = atomicAdd(&hist[b], 1);
        pairs[(size_t)b * BCAP + pos] = (unsigned)s | ((unsigned)(d & 127) << 20);
    }
}

// Exclusive scan of bcount[nbuck] -> bbase; also rowstart[N] = E sentinel.
__global__ __launch_bounds__(1024) void scan_bcount(
    const int* __restrict__ bcount, int* __restrict__ bbase,
    int* __restrict__ rowstart, int N, int E, int nbuck) {
    __shared__ int tmp[1024];
    const int t = threadIdx.x;
    int v = (t < nbuck) ? bcount[t] : 0;
    tmp[t] = v;
    __syncthreads();
    for (int off = 1; off < 1024; off <<= 1) {
        int u = (t >= off) ? tmp[t - off] : 0;
        __syncthreads();
        tmp[t] += u;
        __syncthreads();
    }
    if (t < nbuck) bbase[t] = tmp[t] - v;  // exclusive
    if (t == 0) rowstart[N] = E;
}

// One block per bucket: LDS degree histogram -> scan -> rowstart/dinv,
// then cursor fill of col (contiguous ~8KB window per bucket).
__global__ __launch_bounds__(256) void fill_csr_bucket(
    const unsigned* __restrict__ pairs, const int* __restrict__ bcount,
    const int* __restrict__ bbase, int* __restrict__ rowstart,
    float* __restrict__ dinv, int* __restrict__ col, int N) {
    __shared__ int hist[128], pfx[128];
    const int b = blockIdx.x, t = threadIdx.x;
    if (t < 128) hist[t] = 0;
    __syncthreads();
    const int cnt = bcount[b];
    const unsigned* pp = pairs + (size_t)b * BCAP;
    for (int e = t; e < cnt; e += 256)
        atomicAdd(&hist[pp[e] >> 20], 1);
    __syncthreads();
    if (t < 128) pfx[t] = hist[t];
    __syncthreads();
    for (int off = 1; off < 128; off <<= 1) {
        int v = 0;
        if (t < 128 && t >= off) v = pfx[t - off];
        __syncthreads();
        if (t < 128) pfx[t] += v;
        __syncthreads();
    }
    const int base = bbase[b];
    if (t < 128) {
        int deg = hist[t];
        int start = base + pfx[t] - deg;  // exclusive within bucket
        int n = (b << NB_SHIFT) + t;
        if (n < N) {
            rowstart[n] = start;
            dinv[n] = rsqrtf((float)deg + 1.0f);  // +1 self-loop
        }
        hist[t] = start;  // becomes cursor
    }
    __syncthreads();
    for (int e = t; e < cnt; e += 256) {
        unsigned pr = pp[e];
        int pos = atomicAdd(&hist[pr >> 20], 1);
        col[pos] = (int)(pr & 0xFFFFFu);
    }
}

// hs[row][c] = (X'[row][:] @ W[:][c]) * dinv[row], stored bf16.
// FUSE: X' = prelu(bn(X), a) with scale/shift computed inline from raw stats.
template <int K, bool FUSE>
__global__ __launch_bounds__(256) void gemm_scale(
    const float* __restrict__ X, const float* __restrict__ W,
    const float* __restrict__ dinv, const float* __restrict__ stats_prev,
    const float* __restrict__ g_prev, const float* __restrict__ be_prev,
    const float* __restrict__ a_prev, float invN,
    ushort4* __restrict__ hsb4, int N) {
    static_assert(K % 64 == 0, "K must be multiple of 64");
    __shared__ float Ws[K * 64];
    __shared__ float Xs[64 * 65];
    __shared__ float scs[64], shs[64];

    const int t = threadIdx.x;
    const int rowBase = blockIdx.x * 64;

    if (FUSE && t < 64) {
        float mu = stats_prev[t] * invN;
        float var = stats_prev[64 + t] * invN - mu * mu;
        float sc = g_prev[t] * rsqrtf(var + BN_EPS);
        scs[t] = sc;
        shs[t] = fmaf(-mu, sc, be_prev[t]);
    }

    for (int q = t; q < K * 16; q += 256)
        ((float4*)Ws)[q] = ((const float4*)W)[q];

    const int tx = t & 15;
    const int ty = t >> 4;

    float acc[4][4];
#pragma unroll
    for (int i = 0; i < 4; ++i)
#pragma unroll
        for (int j = 0; j < 4; ++j) acc[i][j] = 0.f;

#pragma unroll
    for (int kh = 0; kh < K / 64; ++kh) {
        __syncthreads();  // covers Ws + scs on first pass
#pragma unroll
        for (int j = 0; j < 4; ++j) {
            int q = t + j * 256;
            int r = q >> 4, kk = q & 15;
            int row = rowBase + r;
            float4 v = make_float4(0.f, 0.f, 0.f, 0.f);
            if (row < N) {
                v = *(const float4*)(X + (size_t)row * K + kh * 64 + kk * 4);
                if (FUSE) {
                    int cg = kh * 16 + kk;  // (K=64 -> kh==0)
                    float4 av = ((const float4*)a_prev)[cg];
                    int c = cg * 4;
                    v.x = fmaf(v.x, scs[c + 0], shs[c + 0]); v.x = v.x >= 0.f ? v.x : av.x * v.x;
                    v.y = fmaf(v.y, scs[c + 1], shs[c + 1]); v.y = v.y >= 0.f ? v.y : av.y * v.y;
                    v.z = fmaf(v.z, scs[c + 2], shs[c + 2]); v.z = v.z >= 0.f ? v.z : av.z * v.z;
                    v.w = fmaf(v.w, scs[c + 3], shs[c + 3]); v.w = v.w >= 0.f ? v.w : av.w * v.w;
                }
            }
            float* p = &Xs[r * 65 + kk * 4];
            p[0] = v.x; p[1] = v.y; p[2] = v.z; p[3] = v.w;
        }
        __syncthreads();
#pragma unroll 8
        for (int k = 0; k < 64; ++k) {
            float4 w4 = *(const float4*)&Ws[(kh * 64 + k) * 64 + tx * 4];
#pragma unroll
            for (int i = 0; i < 4; ++i) {
                float xv = Xs[(ty * 4 + i) * 65 + k];
                acc[i][0] = fmaf(xv, w4.x, acc[i][0]);
                acc[i][1] = fmaf(xv, w4.y, acc[i][1]);
                acc[i][2] = fmaf(xv, w4.z, acc[i][2]);
                acc[i][3] = fmaf(xv, w4.w, acc[i][3]);
            }
        }
    }

#pragma unroll
    for (int i = 0; i < 4; ++i) {
        int row = rowBase + ty * 4 + i;
        if (row < N) {
            float dv = dinv[row];
            ushort4 o;
            o.x = f2bf(acc[i][0] * dv);
            o.y = f2bf(acc[i][1] * dv);
            o.z = f2bf(acc[i][2] * dv);
            o.w = f2bf(acc[i][3] * dv);
            hsb4[(size_t)row * 16 + tx] = o;
        }
    }
}

// One wave per node, 8 edges x 8 feature-lanes (16B/lane gathers).
// y[n] = dinv[n]*(hs[n] + sum hs[src]) + b; fused BN stats.
__global__ __launch_bounds__(256) void aggregate_bn(
    const uint4* __restrict__ hsb16, const int* __restrict__ col,
    const int* __restrict__ rowstart, const float* __restrict__ dinv,
    const float* __restrict__ bias, float* __restrict__ stats,
    float4* __restrict__ y4, int N) {
    const int t = threadIdx.x;
    const int lane = t & 63;
    const int wid = t >> 6;      // wave in block (0..3)
    const int fl = lane & 7;     // 16B feature chunk (features fl*8 .. fl*8+7)
    const int eg = lane >> 3;    // edge subgroup (0..7)

    __shared__ float lsum[64], lsq[64];
    if (t < 64) { lsum[t] = 0.f; lsq[t] = 0.f; }
    __syncthreads();

    float4 s0 = make_float4(0.f, 0.f, 0.f, 0.f);
    float4 s1 = make_float4(0.f, 0.f, 0.f, 0.f);
    float4 q0 = make_float4(0.f, 0.f, 0.f, 0.f);
    float4 q1 = make_float4(0.f, 0.f, 0.f, 0.f);
    const float4 b0 = ((const float4*)bias)[fl * 2];
    const float4 b1 = ((const float4*)bias)[fl * 2 + 1];
    const int waveStride = gridDim.x * 4;

    for (int n = blockIdx.x * 4 + wid; n < N; n += waveStride) {
        int start = rowstart[n];
        int deg = rowstart[n + 1] - start;
        float4 a0 = make_float4(0.f, 0.f, 0.f, 0.f);
        float4 a1 = make_float4(0.f, 0.f, 0.f, 0.f);
        for (int i = eg; i < deg; i += 8) {
            int s = col[start + i];
            uint4 rv = hsb16[(size_t)s * 8 + fl];
            a0.x += bf_lo(rv.x); a0.y += bf_hi(rv.x);
            a0.z += bf_lo(rv.y); a0.w += bf_hi(rv.y);
            a1.x += bf_lo(rv.z); a1.y += bf_hi(rv.z);
            a1.z += bf_lo(rv.w); a1.w += bf_hi(rv.w);
        }
        // reduce across 8 edge subgroups (xor lanes 8, 16, 32)
#pragma unroll
        for (int off = 8; off <= 32; off <<= 1) {
            a0.x += __shfl_xor(a0.x, off); a0.y += __shfl_xor(a0.y, off);
            a0.z += __shfl_xor(a0.z, off); a0.w += __shfl_xor(a0.w, off);
            a1.x += __shfl_xor(a1.x, off); a1.y += __shfl_xor(a1.y, off);
            a1.z += __shfl_xor(a1.z, off); a1.w += __shfl_xor(a1.w, off);
        }
        if (eg == 0) {
            uint4 sv = hsb16[(size_t)n * 8 + fl];
            float dv = dinv[n];
            float4 y0, y1;
            y0.x = fmaf(dv, a0.x + bf_lo(sv.x), b0.x);
            y0.y = fmaf(dv, a0.y + bf_hi(sv.x), b0.y);
            y0.z = fmaf(dv, a0.z + bf_lo(sv.y), b0.z);
            y0.w = fmaf(dv, a0.w + bf_hi(sv.y), b0.w);
            y1.x = fmaf(dv, a1.x + bf_lo(sv.z), b1.x);
            y1.y = fmaf(dv, a1.y + bf_hi(sv.z), b1.y);
            y1.z = fmaf(dv, a1.z + bf_lo(sv.w), b1.z);
            y1.w = fmaf(dv, a1.w + bf_hi(sv.w), b1.w);
            y4[(size_t)n * 16 + fl * 2] = y0;
            y4[(size_t)n * 16 + fl * 2 + 1] = y1;
            s0.x += y0.x; s0.y += y0.y; s0.z += y0.z; s0.w += y0.w;
            s1.x += y1.x; s1.y += y1.y; s1.z += y1.z; s1.w += y1.w;
            q0.x = fmaf(y0.x, y0.x, q0.x); q0.y = fmaf(y0.y, y0.y, q0.y);
            q0.z = fmaf(y0.z, y0.z, q0.z); q0.w = fmaf(y0.w, y0.w, q0.w);
            q1.x = fmaf(y1.x, y1.x, q1.x); q1.y = fmaf(y1.y, y1.y, q1.y);
            q1.z = fmaf(y1.z, y1.z, q1.z); q1.w = fmaf(y1.w, y1.w, q1.w);
        }
    }
    if (eg == 0) {
        int c = fl * 8;
        atomicAdd(&lsum[c + 0], s0.x); atomicAdd(&lsum[c + 1], s0.y);
        atomicAdd(&lsum[c + 2], s0.z); atomicAdd(&lsum[c + 3], s0.w);
        atomicAdd(&lsum[c + 4], s1.x); atomicAdd(&lsum[c + 5], s1.y);
        atomicAdd(&lsum[c + 6], s1.z); atomicAdd(&lsum[c + 7], s1.w);
        atomicAdd(&lsq[c + 0], q0.x);  atomicAdd(&lsq[c + 1], q0.y);
        atomicAdd(&lsq[c + 2], q0.z);  atomicAdd(&lsq[c + 3], q0.w);
        atomicAdd(&lsq[c + 4], q1.x);  atomicAdd(&lsq[c + 5], q1.y);
        atomicAdd(&lsq[c + 6], q1.z);  atomicAdd(&lsq[c + 7], q1.w);
    }
    __syncthreads();
    if (t < 64) atomicAdd(&stats[t], lsum[t]);
    else if (t < 128) atomicAdd(&stats[64 + (t - 64)], lsq[t - 64]);
}

// final layer: out = prelu(bn(y), a), scale/shift inline from raw stats
__global__ __launch_bounds__(256) void bn_apply(
    const float4* __restrict__ y4, const float* __restrict__ stats,
    const float* __restrict__ g, const float* __restrict__ be,
    const float* __restrict__ a, float invN, float4* __restrict__ out4,
    int total4) {
    int i = blockIdx.x * blockDim.x + threadIdx.x;
    if (i >= total4) return;
    int cg = (i & 15) * 4;
    float4 v = y4[i];
    float4 o;
#pragma unroll
    for (int j = 0; j < 4; ++j) {
        int c = cg + j;
        float mu = stats[c] * invN;
        float var = stats[64 + c] * invN - mu * mu;
        float sc = g[c] * rsqrtf(var + BN_EPS);
        float sh = fmaf(-mu, sc, be[c]);
        float vv = j == 0 ? v.x : j == 1 ? v.y : j == 2 ? v.z : v.w;
        float z = fmaf(vv, sc, sh);
        z = z >= 0.f ? z : a[c] * z;
        if (j == 0) o.x = z; else if (j == 1) o.y = z; else if (j == 2) o.z = z; else o.w = z;
    }
    out4[i] = o;
}

extern "C" void kernel_launch(void* const* d_in, const int* in_sizes, int n_in,
                              void* d_out, int out_size, void* d_ws, size_t ws_size,
                              hipStream_t stream) {
    const float* x  = (const float*)d_in[0];
    const int*   ei = (const int*)d_in[1];
    const int N = in_sizes[0] / 128;
    const int E = in_sizes[1] / 2;
    const int* srcp = ei;
    const int* dstp = ei + E;

    const float* W1 = (const float*)d_in[2];
    const float* b1 = (const float*)d_in[3];
    const float* g1 = (const float*)d_in[4];
    const float* be1 = (const float*)d_in[5];
    const float* a1 = (const float*)d_in[6];
    const float* W2 = (const float*)d_in[7];
    const float* b2 = (const float*)d_in[8];
    const float* g2 = (const float*)d_in[9];
    const float* be2 = (const float*)d_in[10];
    const float* a2 = (const float*)d_in[11];
    const float* W3 = (const float*)d_in[12];
    const float* b3 = (const float*)d_in[13];
    const float* g3 = (const float*)d_in[14];
    const float* be3 = (const float*)d_in[15];
    const float* a3 = (const float*)d_in[16];

    const int nbuck = (N + 127) >> NB_SHIFT;  // 782

    // ws layout (4B units):
    // dinv[N] | rowstart[N+4] | bcount[1024] | bbase[1024] | stats[768] |
    // col[E] | pairs[nbuck*BCAP] | hsb[N*32] | ybuf[N*64]
    float* ws = (float*)d_ws;
    float* dinv     = ws;
    int*   rowstart = (int*)(ws + N);
    int*   bcount   = (int*)(ws + 2 * (size_t)N + 4);
    int*   bbase    = bcount + 1024;
    float* stats    = (float*)(bbase + 1024);
    int*   col      = (int*)(stats + 768);
    unsigned* pairs = (unsigned*)(col + E);
    float* hsbf     = (float*)(pairs + (size_t)nbuck * BCAP);
    ushort4* hsb4   = (ushort4*)hsbf;
    float* ybuf     = hsbf + (size_t)N * 32;

    float* stats1 = stats, *stats2 = stats + 256, *stats3 = stats + 512;

    // one memset covers bcount + bbase + stats (contiguous)
    hipMemsetAsync(bcount, 0, (1024 + 1024 + 768) * sizeof(int), stream);
    partition_edges<<<(E + PART_CHUNK - 1) / PART_CHUNK, 256, 0, stream>>>(
        srcp, dstp, bcount, pairs, E, nbuck);
    scan_bcount<<<1, 1024, 0, stream>>>(bcount, bbase, rowstart, N, E, nbuck);
    fill_csr_bucket<<<nbuck, 256, 0, stream>>>(pairs, bcount, bbase, rowstart,
                                               dinv, col, N);

    const int gemmGrid = (N + 63) / 64;
    const int aggGrid = 2048;
    const int applyGrid = (N * 16 + 255) / 256;
    const float invN = 1.0f / (float)N;

    // ---- layer 1 ----
    gemm_scale<128, false><<<gemmGrid, 256, 0, stream>>>(
        x, W1, dinv, nullptr, nullptr, nullptr, nullptr, invN, hsb4, N);
    aggregate_bn<<<aggGrid, 256, 0, stream>>>((const uint4*)hsb4, col, rowstart,
                                              dinv, b1, stats1, (float4*)ybuf, N);

    // ---- layer 2 (BN1+PReLU1 inlined into X staging) ----
    gemm_scale<64, true><<<gemmGrid, 256, 0, stream>>>(
        ybuf, W2, dinv, stats1, g1, be1, a1, invN, hsb4, N);
    aggregate_bn<<<aggGrid, 256, 0, stream>>>((const uint4*)hsb4, col, rowstart,
                                              dinv, b2, stats2, (float4*)ybuf, N);

    // ---- layer 3 ----
    gemm_scale<64, true><<<gemmGrid, 256, 0, stream>>>(
        ybuf, W3, dinv, stats2, g2, be2, a2, invN, hsb4, N);
    aggregate_bn<<<aggGrid, 256, 0, stream>>>((const uint4*)hsb4, col, rowstart,
                                              dinv, b3, stats3, (float4*)ybuf, N);

    bn_apply<<<applyGrid, 256, 0, stream>>>((const float4*)ybuf, stats3, g3, be3,
                                            a3, invN, (float4*)d_out, N * 16);
}

// Round 9
// 578.316 us; speedup vs baseline: 1.3290x; 1.0513x over previous
//
#include <hip/hip_runtime.h>

// GCN: 3 x (GCNConv -> BN(train) -> PReLU), N=100000, E=1600000, 128->64->64->64
// R9: (1) aggregate reverted to R4's measured-optimal gather geometry
//     (16 lanes x 8B per edge, depth-1: 100us, FETCH 90MB — 4-in-flight is the
//     sweet spot; 8-in-flight via depth(R5) or width(R8) both = 116us/160MB).
//     (2) GEMMs switched from fp32 vector (~150us total, LDS-read bound) to
//     bf16 MFMA 16x16x32 (inputs already rounded to bf16 downstream; fp32 acc).
// R3 lesson: per-bucket LDS-atomic aggregation = latency disaster.
// R6/R7 lesson: gather locality engineering cannot beat ~100us (per-XCD
//     compulsory table traffic); leave the gather alone.

constexpr float BN_EPS = 1e-5f;
constexpr int NB_SHIFT = 7;          // 128 nodes per bucket
constexpr int BCAP = 2560;           // pairs per bucket (avg 2048, ~11 sigma)
constexpr int PART_CHUNK = 8192;     // edges per partition block

typedef __bf16 bf16x8 __attribute__((ext_vector_type(8)));
typedef float floatx4 __attribute__((ext_vector_type(4)));

__device__ inline float bf2f(unsigned short h) {
    return __uint_as_float(((unsigned)h) << 16);
}
__device__ inline unsigned short f2bf(float f) {
    unsigned u = __float_as_uint(f);
    unsigned r = (u + 0x7FFFu + ((u >> 16) & 1u)) >> 16;
    return (unsigned short)r;
}

// Partition edges into 128-node dst-buckets; packed entry = src | (local<<20).
__global__ __launch_bounds__(256) void partition_edges(
    const int* __restrict__ src, const int* __restrict__ dst,
    int* __restrict__ bcount, unsigned* __restrict__ pairs, int E, int nbuck) {
    __shared__ int hist[1024];
    const int t = threadIdx.x;
    for (int i = t; i < nbuck; i += 256) hist[i] = 0;
    __syncthreads();
    const int e0 = blockIdx.x * PART_CHUNK;
    const int e1 = min(e0 + PART_CHUNK, E);
    for (int e = e0 + t; e < e1; e += 256)
        atomicAdd(&hist[dst[e] >> NB_SHIFT], 1);
    __syncthreads();
    for (int i = t; i < nbuck; i += 256) {
        int c = hist[i];
        hist[i] = (c > 0) ? atomicAdd(&bcount[i], c) : 0;  // run base within bucket
    }
    __syncthreads();
    for (int e = e0 + t; e < e1; e += 256) {
        int s = src[e], d = dst[e];
        int b = d >> NB_SHIFT;
        int pos = atomicAdd(&hist[b], 1);
        pairs[(size_t)b * BCAP + pos] = (unsigned)s | ((unsigned)(d & 127) << 20);
    }
}

// Exclusive scan of bcount[nbuck] -> bbase; also rowstart[N] = E sentinel.
__global__ __launch_bounds__(1024) void scan_bcount(
    const int* __restrict__ bcount, int* __restrict__ bbase,
    int* __restrict__ rowstart, int N, int E, int nbuck) {
    __shared__ int tmp[1024];
    const int t = threadIdx.x;
    int v = (t < nbuck) ? bcount[t] : 0;
    tmp[t] = v;
    __syncthreads();
    for (int off = 1; off < 1024; off <<= 1) {
        int u = (t >= off) ? tmp[t - off] : 0;
        __syncthreads();
        tmp[t] += u;
        __syncthreads();
    }
    if (t < nbuck) bbase[t] = tmp[t] - v;  // exclusive
    if (t == 0) rowstart[N] = E;
}

// One block per bucket: LDS degree histogram -> scan -> rowstart/dinv,
// then cursor fill of col (contiguous ~8KB window per bucket).
__global__ __launch_bounds__(256) void fill_csr_bucket(
    const unsigned* __restrict__ pairs, const int* __restrict__ bcount,
    const int* __restrict__ bbase, int* __restrict__ rowstart,
    float* __restrict__ dinv, int* __restrict__ col, int N) {
    __shared__ int hist[128], pfx[128];
    const int b = blockIdx.x, t = threadIdx.x;
    if (t < 128) hist[t] = 0;
    __syncthreads();
    const int cnt = bcount[b];
    const unsigned* pp = pairs + (size_t)b * BCAP;
    for (int e = t; e < cnt; e += 256)
        atomicAdd(&hist[pp[e] >> 20], 1);
    __syncthreads();
    if (t < 128) pfx[t] = hist[t];
    __syncthreads();
    for (int off = 1; off < 128; off <<= 1) {
        int v = 0;
        if (t < 128 && t >= off) v = pfx[t - off];
        __syncthreads();
        if (t < 128) pfx[t] += v;
        __syncthreads();
    }
    const int base = bbase[b];
    if (t < 128) {
        int deg = hist[t];
        int start = base + pfx[t] - deg;  // exclusive within bucket
        int n = (b << NB_SHIFT) + t;
        if (n < N) {
            rowstart[n] = start;
            dinv[n] = rsqrtf((float)deg + 1.0f);  // +1 self-loop
        }
        hist[t] = start;  // becomes cursor
    }
    __syncthreads();
    for (int e = t; e < cnt; e += 256) {
        unsigned pr = pp[e];
        int pos = atomicAdd(&hist[pr >> 20], 1);
        col[pos] = (int)(pr & 0xFFFFFu);
    }
}

// Transpose + bf16-convert all three W matrices: wt[n*K + k] = bf16(W[k][n]).
__global__ __launch_bounds__(256) void prep_wt_all(
    const float* __restrict__ W1, const float* __restrict__ W2,
    const float* __restrict__ W3, unsigned short* __restrict__ wt1,
    unsigned short* __restrict__ wt2, unsigned short* __restrict__ wt3) {
    const int b = blockIdx.x, t = threadIdx.x;
    const float* W;
    unsigned short* wt;
    int K, base;
    if (b < 32)      { W = W1; wt = wt1; K = 128; base = b * 256; }
    else if (b < 48) { W = W2; wt = wt2; K = 64;  base = (b - 32) * 256; }
    else             { W = W3; wt = wt3; K = 64;  base = (b - 48) * 256; }
    int i = base + t;
    if (i < K * 64) {
        int k = i >> 6, n = i & 63;
        wt[n * K + k] = f2bf(W[i]);
    }
}

// MFMA bf16 GEMM: hs[row][c] = bf16( (X'[row][:] @ W[:][c]) * dinv[row] ).
// FUSE: X' = prelu(bn(X), a) with scale/shift computed inline from raw stats.
// Block: 256 thr = 4 waves; 64 rows x 64 cols; wave w owns rows 16w..16w+15.
template <int K, bool FUSE>
__global__ __launch_bounds__(256) void gemm_mfma(
    const float* __restrict__ X, const unsigned short* __restrict__ wt,
    const float* __restrict__ dinv, const float* __restrict__ stats_prev,
    const float* __restrict__ g_prev, const float* __restrict__ be_prev,
    const float* __restrict__ a_prev, float invN,
    ushort4* __restrict__ hsb4, int N) {
    constexpr int XS = K + 8;  // LDS row stride in bf16 units (pad 16B)
    __shared__ unsigned short Xs[64 * XS];
    __shared__ unsigned short Wts[64 * XS];
    __shared__ float scs[64], shs[64];

    const int t = threadIdx.x;
    const int rowBase = blockIdx.x * 64;

    if (FUSE && t < 64) {
        float mu = stats_prev[t] * invN;
        float var = stats_prev[64 + t] * invN - mu * mu;
        float sc = g_prev[t] * rsqrtf(var + BN_EPS);
        scs[t] = sc;
        shs[t] = fmaf(-mu, sc, be_prev[t]);
    }

    // stage Wt (64 rows x K bf16) via uint4
    constexpr int U4R = K / 8;  // uint4 per wt row
#pragma unroll
    for (int j = 0; j < (64 * U4R) / 256; ++j) {
        int idx = t + j * 256;
        int n = idx / U4R, ch = idx % U4R;
        uint4 v = *(const uint4*)&wt[n * K + ch * 8];
        *(uint4*)&Wts[n * XS + ch * 8] = v;
    }
    __syncthreads();  // scs + Wts visible

    // stage Xs: 64 rows x K fp32 -> (FUSE transform) -> bf16
    constexpr int F4R = K / 4;  // float4 per X row
#pragma unroll
    for (int j = 0; j < (64 * F4R) / 256; ++j) {
        int idx = t + j * 256;
        int r = idx / F4R, c4 = idx % F4R;
        int row = rowBase + r;
        float4 v = make_float4(0.f, 0.f, 0.f, 0.f);
        if (row < N) {
            v = *(const float4*)(X + (size_t)row * K + c4 * 4);
            if (FUSE) {
                int c = c4 * 4;
                float4 av = ((const float4*)a_prev)[c4];
                v.x = fmaf(v.x, scs[c + 0], shs[c + 0]); v.x = v.x >= 0.f ? v.x : av.x * v.x;
                v.y = fmaf(v.y, scs[c + 1], shs[c + 1]); v.y = v.y >= 0.f ? v.y : av.y * v.y;
                v.z = fmaf(v.z, scs[c + 2], shs[c + 2]); v.z = v.z >= 0.f ? v.z : av.z * v.z;
                v.w = fmaf(v.w, scs[c + 3], shs[c + 3]); v.w = v.w >= 0.f ? v.w : av.w * v.w;
            }
        }
        ushort4 o;
        o.x = f2bf(v.x); o.y = f2bf(v.y); o.z = f2bf(v.z); o.w = f2bf(v.w);
        *(ushort4*)&Xs[r * XS + c4 * 4] = o;
    }
    __syncthreads();

    const int w = t >> 6;        // wave 0..3 -> rows 16w..16w+15
    const int l = t & 63;
    const int q = l >> 4;        // quad: k-offset q*8
    const int m = l & 15;        // A row / B col within tile

    floatx4 acc[4];
#pragma unroll
    for (int ct = 0; ct < 4; ++ct) acc[ct] = {0.f, 0.f, 0.f, 0.f};

#pragma unroll
    for (int ks = 0; ks < K / 32; ++ks) {
        bf16x8 a = *(const bf16x8*)&Xs[(16 * w + m) * XS + ks * 32 + q * 8];
#pragma unroll
        for (int ct = 0; ct < 4; ++ct) {
            bf16x8 b = *(const bf16x8*)&Wts[(ct * 16 + m) * XS + ks * 32 + q * 8];
            acc[ct] = __builtin_amdgcn_mfma_f32_16x16x32_bf16(a, b, acc[ct], 0, 0, 0);
        }
    }

    // dinv per owned row (C/D layout: row = q*4 + r, col = m)
    float dv[4];
#pragma unroll
    for (int r = 0; r < 4; ++r) {
        int row = rowBase + 16 * w + q * 4 + r;
        dv[r] = (row < N) ? dinv[row] : 0.f;
    }

    __syncthreads();  // done reading Xs; reuse as C staging (64 x 72 bf16)
    unsigned short* Cs = Xs;
#pragma unroll
    for (int ct = 0; ct < 4; ++ct)
#pragma unroll
        for (int r = 0; r < 4; ++r)
            Cs[(16 * w + q * 4 + r) * 72 + ct * 16 + m] = f2bf(acc[ct][r] * dv[r]);
    __syncthreads();

    // coalesced write-out: 64 rows x 8 uint4 (row = 64 bf16)
#pragma unroll
    for (int j = 0; j < 2; ++j) {
        int idx = t + j * 256;
        int r = idx >> 3, ch = idx & 7;
        int row = rowBase + r;
        if (row < N) {
            uint4 v = *(const uint4*)&Cs[r * 72 + ch * 8];
            ((uint4*)hsb4)[(size_t)row * 8 + ch] = v;
        }
    }
}

// One wave per node, 16 lanes x 8B per edge (R4's measured-optimal geometry).
// y[n] = dinv[n]*(hs[n] + sum hs[src]) + b; fused raw BN stats.
__global__ __launch_bounds__(256) void aggregate_bn(
    const ushort4* __restrict__ hsb4, const int* __restrict__ col,
    const int* __restrict__ rowstart, const float* __restrict__ dinv,
    const float* __restrict__ bias, float* __restrict__ stats,
    float4* __restrict__ y4, int N) {
    const int t = threadIdx.x;
    const int lane = t & 63;
    const int wid = t >> 6;      // wave in block (0..3)
    const int fl = lane & 15;    // float4 feature index
    const int eg = lane >> 4;    // edge subgroup (0..3)

    __shared__ float lsum[64], lsq[64];
    if (t < 64) { lsum[t] = 0.f; lsq[t] = 0.f; }
    __syncthreads();

    float4 ssum = make_float4(0.f, 0.f, 0.f, 0.f);
    float4 ssq  = make_float4(0.f, 0.f, 0.f, 0.f);
    const float4 b4 = ((const float4*)bias)[fl];
    const int waveStride = gridDim.x * 4;

    for (int n = blockIdx.x * 4 + wid; n < N; n += waveStride) {
        int start = rowstart[n];
        int deg = rowstart[n + 1] - start;
        float4 acc = make_float4(0.f, 0.f, 0.f, 0.f);
        for (int i = eg; i < deg; i += 4) {
            int s = col[start + i];
            ushort4 rv = hsb4[(size_t)s * 16 + fl];
            acc.x += bf2f(rv.x); acc.y += bf2f(rv.y);
            acc.z += bf2f(rv.z); acc.w += bf2f(rv.w);
        }
        acc.x += __shfl_xor(acc.x, 16); acc.y += __shfl_xor(acc.y, 16);
        acc.z += __shfl_xor(acc.z, 16); acc.w += __shfl_xor(acc.w, 16);
        acc.x += __shfl_xor(acc.x, 32); acc.y += __shfl_xor(acc.y, 32);
        acc.z += __shfl_xor(acc.z, 32); acc.w += __shfl_xor(acc.w, 32);
        if (eg == 0) {
            ushort4 sv = hsb4[(size_t)n * 16 + fl];
            float dv = dinv[n];
            float4 yv;
            yv.x = fmaf(dv, acc.x + bf2f(sv.x), b4.x);
            yv.y = fmaf(dv, acc.y + bf2f(sv.y), b4.y);
            yv.z = fmaf(dv, acc.z + bf2f(sv.z), b4.z);
            yv.w = fmaf(dv, acc.w + bf2f(sv.w), b4.w);
            y4[(size_t)n * 16 + fl] = yv;
            ssum.x += yv.x; ssum.y += yv.y; ssum.z += yv.z; ssum.w += yv.w;
            ssq.x = fmaf(yv.x, yv.x, ssq.x); ssq.y = fmaf(yv.y, yv.y, ssq.y);
            ssq.z = fmaf(yv.z, yv.z, ssq.z); ssq.w = fmaf(yv.w, yv.w, ssq.w);
        }
    }
    if (eg == 0) {
        atomicAdd(&lsum[fl * 4 + 0], ssum.x); atomicAdd(&lsum[fl * 4 + 1], ssum.y);
        atomicAdd(&lsum[fl * 4 + 2], ssum.z); atomicAdd(&lsum[fl * 4 + 3], ssum.w);
        atomicAdd(&lsq[fl * 4 + 0], ssq.x);  atomicAdd(&lsq[fl * 4 + 1], ssq.y);
        atomicAdd(&lsq[fl * 4 + 2], ssq.z);  atomicAdd(&lsq[fl * 4 + 3], ssq.w);
    }
    __syncthreads();
    if (t < 64) atomicAdd(&stats[t], lsum[t]);
    else if (t < 128) atomicAdd(&stats[64 + (t - 64)], lsq[t - 64]);
}

// final layer: out = prelu(bn(y), a), scale/shift inline from raw stats
__global__ __launch_bounds__(256) void bn_apply(
    const float4* __restrict__ y4, const float* __restrict__ stats,
    const float* __restrict__ g, const float* __restrict__ be,
    const float* __restrict__ a, float invN, float4* __restrict__ out4,
    int total4) {
    int i = blockIdx.x * blockDim.x + threadIdx.x;
    if (i >= total4) return;
    int cg = (i & 15) * 4;
    float4 v = y4[i];
    float4 o;
#pragma unroll
    for (int j = 0; j < 4; ++j) {
        int c = cg + j;
        float mu = stats[c] * invN;
        float var = stats[64 + c] * invN - mu * mu;
        float sc = g[c] * rsqrtf(var + BN_EPS);
        float sh = fmaf(-mu, sc, be[c]);
        float vv = j == 0 ? v.x : j == 1 ? v.y : j == 2 ? v.z : v.w;
        float z = fmaf(vv, sc, sh);
        z = z >= 0.f ? z : a[c] * z;
        if (j == 0) o.x = z; else if (j == 1) o.y = z; else if (j == 2) o.z = z; else o.w = z;
    }
    out4[i] = o;
}

extern "C" void kernel_launch(void* const* d_in, const int* in_sizes, int n_in,
                              void* d_out, int out_size, void* d_ws, size_t ws_size,
                              hipStream_t stream) {
    const float* x  = (const float*)d_in[0];
    const int*   ei = (const int*)d_in[1];
    const int N = in_sizes[0] / 128;
    const int E = in_sizes[1] / 2;
    const int* srcp = ei;
    const int* dstp = ei + E;

    const float* W1 = (const float*)d_in[2];
    const float* b1 = (const float*)d_in[3];
    const float* g1 = (const float*)d_in[4];
    const float* be1 = (const float*)d_in[5];
    const float* a1 = (const float*)d_in[6];
    const float* W2 = (const float*)d_in[7];
    const float* b2 = (const float*)d_in[8];
    const float* g2 = (const float*)d_in[9];
    const float* be2 = (const float*)d_in[10];
    const float* a2 = (const float*)d_in[11];
    const float* W3 = (const float*)d_in[12];
    const float* b3 = (const float*)d_in[13];
    const float* g3 = (const float*)d_in[14];
    const float* be3 = (const float*)d_in[15];
    const float* a3 = (const float*)d_in[16];

    const int nbuck = (N + 127) >> NB_SHIFT;  // 782

    // ws layout (4B units):
    // dinv[N] | rowstart[N+4] | bcount[1024] | bbase[1024] | stats[768] |
    // wt1[4096] wt2[2048] wt3[2048] | col[E] | pairs[nbuck*BCAP] |
    // hsb[N*32] | ybuf[N*64]
    float* ws = (float*)d_ws;
    float* dinv     = ws;
    int*   rowstart = (int*)(ws + N);
    int*   bcount   = (int*)(ws + 2 * (size_t)N + 4);
    int*   bbase    = bcount + 1024;
    float* stats    = (float*)(bbase + 1024);
    unsigned short* wt1 = (unsigned short*)(stats + 768);
    unsigned short* wt2 = wt1 + 8192;
    unsigned short* wt3 = wt2 + 4096;
    int*   col      = (int*)(stats + 768 + 8192);
    unsigned* pairs = (unsigned*)(col + E);
    float* hsbf     = (float*)(pairs + (size_t)nbuck * BCAP);
    ushort4* hsb4   = (ushort4*)hsbf;
    float* ybuf     = hsbf + (size_t)N * 32;

    float* stats1 = stats, *stats2 = stats + 256, *stats3 = stats + 512;

    // one memset covers bcount + bbase + stats (contiguous)
    hipMemsetAsync(bcount, 0, (1024 + 1024 + 768) * sizeof(int), stream);
    prep_wt_all<<<64, 256, 0, stream>>>(W1, W2, W3, wt1, wt2, wt3);
    partition_edges<<<(E + PART_CHUNK - 1) / PART_CHUNK, 256, 0, stream>>>(
        srcp, dstp, bcount, pairs, E, nbuck);
    scan_bcount<<<1, 1024, 0, stream>>>(bcount, bbase, rowstart, N, E, nbuck);
    fill_csr_bucket<<<nbuck, 256, 0, stream>>>(pairs, bcount, bbase, rowstart,
                                               dinv, col, N);

    const int gemmGrid = (N + 63) / 64;
    const int aggGrid = 2048;
    const int applyGrid = (N * 16 + 255) / 256;
    const float invN = 1.0f / (float)N;

    // ---- layer 1 ----
    gemm_mfma<128, false><<<gemmGrid, 256, 0, stream>>>(
        x, wt1, dinv, nullptr, nullptr, nullptr, nullptr, invN, hsb4, N);
    aggregate_bn<<<aggGrid, 256, 0, stream>>>(hsb4, col, rowstart, dinv, b1,
                                              stats1, (float4*)ybuf, N);

    // ---- layer 2 (BN1+PReLU1 inlined into X staging) ----
    gemm_mfma<64, true><<<gemmGrid, 256, 0, stream>>>(
        ybuf, wt2, dinv, stats1, g1, be1, a1, invN, hsb4, N);
    aggregate_bn<<<aggGrid, 256, 0, stream>>>(hsb4, col, rowstart, dinv, b2,
                                              stats2, (float4*)ybuf, N);

    // ---- layer 3 ----
    gemm_mfma<64, true><<<gemmGrid, 256, 0, stream>>>(
        ybuf, wt3, dinv, stats2, g2, be2, a2, invN, hsb4, N);
    aggregate_bn<<<aggGrid, 256, 0, stream>>>(hsb4, col, rowstart, dinv, b3,
                                              stats3, (float4*)ybuf, N);

    bn_apply<<<applyGrid, 256, 0, stream>>>((const float4*)ybuf, stats3, g3, be3,
                                            a3, invN, (float4*)d_out, N * 16);
}